// Round 2
// baseline (461.462 us; speedup 1.0000x reference)
//
#include <hip/hip_runtime.h>
#include <stdint.h>

typedef int i32x4 __attribute__((ext_vector_type(4)));
typedef unsigned short u16x8 __attribute__((ext_vector_type(8)));

#define N_TOK 2048
#define HID   4096
#define INTER 11008
#define TWOI  22016
#define KT1   32      // HID/128
#define KT2   86      // INTER/128

#define GLD16(gp, lp) __builtin_amdgcn_global_load_lds( \
    (const __attribute__((address_space(1))) void*)(gp), \
    (__attribute__((address_space(3))) void*)(lp), 16, 0, 0)

__device__ __forceinline__ unsigned short f2bf(float f) {
  uint32_t u = __float_as_uint(f);
  uint32_t r = (u + 0x7fffu + ((u >> 16) & 1u)) >> 16;
  return (unsigned short)r;
}

// ---------------------------------------------------------------------------
// Pack int32 [R][K] -> int8 tiled [R/128][K/128][128][128], interior bytes
// pre-XOR-swizzled: stored[row][c'] = src[row][c' ^ ((row&7)<<4)]. GEMM LDS
// staging is then a linear copy; swizzled ds_read_b128 is conflict-free.
// ---------------------------------------------------------------------------
__global__ __launch_bounds__(256) void pack_tiled(
    const int* __restrict__ src, uint8_t* __restrict__ dst, int K, int KT)
{
  const long u = (long)blockIdx.x * 256 + threadIdx.x;
  const long tile = u >> 10;
  const int within = (int)(u & 1023);
  const int row = within >> 3;
  const int swc = (within & 7) << 4;
  const int col = swc ^ ((row & 7) << 4);
  const long tR = tile / KT;
  const long tK = tile - tR * KT;
  const int* s = src + (tR * 128 + row) * (long)K + tK * 128 + col;
  i32x4 o;
#pragma unroll
  for (int q = 0; q < 4; ++q) {
    i32x4 w = *reinterpret_cast<const i32x4*>(s + q * 4);
    o[q] = (w[0] & 255) | ((w[1] & 255) << 8) | ((w[2] & 255) << 16)
         | ((w[3] & 255) << 24);
  }
  *reinterpret_cast<i32x4*>(dst + tile * 16384 + (long)within * 16) = o;
}

__global__ __launch_bounds__(1024) void zero_mx(float* __restrict__ mx) {
  const int i = blockIdx.x * 1024 + threadIdx.x;
  if (i < N_TOK) mx[i] = 0.0f;
}

// ---------------------------------------------------------------------------
// GEMM1: 256x256 tile, 8 waves (2Mx4N), BK=128B, dbuf LDS w/ 1-group prefetch
// distance. B pairs gate tile (rowTile nt) with up tile (rowTile 86+nt).
// Epilogue: gate waves dequant->LDS; up waves compute silu(g)*u, write act
// bf16 [N][I], per-row atomicMax |act| -> mx.
// ---------------------------------------------------------------------------
__global__ __launch_bounds__(512, 2) void gemm1_k(
    const uint8_t* __restrict__ x8t, const uint8_t* __restrict__ wg8t,
    const float* __restrict__ xs, const float* __restrict__ wgs,
    unsigned short* __restrict__ act, float* __restrict__ mx)
{
  __shared__ uint8_t sm[131072];
  const int tid = threadIdx.x;
  const int lane = tid & 63, wid = tid >> 6;
  const int wgm = wid >> 2, wgn = wid & 3;
  const int mt = blockIdx.x, nt = blockIdx.y;
  const int r15 = lane & 15;
  const int sxo = (r15 & 7) << 4;
  const int khi = (lane >> 4) << 4;

  const uint8_t* pA0 = x8t  + ((size_t)(2 * mt)     * KT1) * 16384 + tid * 16;
  const uint8_t* pA1 = x8t  + ((size_t)(2 * mt + 1) * KT1) * 16384 + tid * 16;
  const uint8_t* pB0 = wg8t + ((size_t)nt           * KT1) * 16384 + tid * 16;
  const uint8_t* pB1 = wg8t + ((size_t)(86 + nt)    * KT1) * 16384 + tid * 16;

  const int aoff = ((wgm << 7) + r15) << 7;            // (wgm*128+r15)*128
  const int boff = 32768 + (((wgn << 6) + r15) << 7);  // B region offset

  i32x4 acc[8][4] = {};

#define STAGE1(kt, buf) do {                                   \
    uint8_t* l = sm + (buf) * 65536;                           \
    const size_t S = (size_t)(kt) * 16384;                     \
    GLD16(pA0 + S,        l + tid * 16);                       \
    GLD16(pA0 + S + 8192, l + tid * 16 + 8192);                \
    GLD16(pA1 + S,        l + tid * 16 + 16384);               \
    GLD16(pA1 + S + 8192, l + tid * 16 + 24576);               \
    GLD16(pB0 + S,        l + tid * 16 + 32768);               \
    GLD16(pB0 + S + 8192, l + tid * 16 + 40960);               \
    GLD16(pB1 + S,        l + tid * 16 + 49152);               \
    GLD16(pB1 + S + 8192, l + tid * 16 + 57344);               \
  } while (0)

  STAGE1(0, 0);
  __syncthreads();

  for (int kt = 0; kt < KT1; ++kt) {
    if (kt + 1 < KT1) STAGE1(kt + 1, (kt + 1) & 1);
    const uint8_t* bufc = sm + (kt & 1) * 65536;
#pragma unroll
    for (int kk = 0; kk < 2; ++kk) {
      const int cs = (khi + kk * 64) ^ sxo;
      i32x4 bv[4];
#pragma unroll
      for (int n = 0; n < 4; ++n)
        bv[n] = *reinterpret_cast<const i32x4*>(bufc + boff + n * 2048 + cs);
#pragma unroll
      for (int mh = 0; mh < 2; ++mh) {
        i32x4 av[4];
#pragma unroll
        for (int m = 0; m < 4; ++m)
          av[m] = *reinterpret_cast<const i32x4*>(
              bufc + aoff + (mh * 4 + m) * 2048 + cs);
        __builtin_amdgcn_s_setprio(1);
#pragma unroll
        for (int m = 0; m < 4; ++m)
#pragma unroll
          for (int n = 0; n < 4; ++n)
            acc[mh * 4 + m][n] = __builtin_amdgcn_mfma_i32_16x16x64_i8(
                av[m], bv[n], acc[mh * 4 + m][n], 0, 0, 0);
        __builtin_amdgcn_s_setprio(0);
      }
    }
    __syncthreads();
  }
#undef STAGE1

  // ---- fused epilogue: silu(gate)*up + rowmax ----
  float* gs = (float*)sm;                 // [256][128] f32, 2-way swizzled
  const int rq = (lane >> 4) << 2;
  if (wgn < 2) {
#pragma unroll
    for (int m = 0; m < 8; ++m) {
#pragma unroll
      for (int n = 0; n < 4; ++n) {
        const int coll = (wgn << 6) + n * 16 + r15;        // 0..127
        const float wsc = wgs[nt * 128 + coll];
#pragma unroll
        for (int r = 0; r < 4; ++r) {
          const int rowl = (wgm << 7) + m * 16 + rq + r;
          const float g = (float)acc[m][n][r] * xs[mt * 256 + rowl] * wsc;
          gs[rowl * 128 + (coll ^ (((rowl >> 2) & 1) << 4))] = g;
        }
      }
    }
  }
  __syncthreads();
  if (wgn >= 2) {
#pragma unroll
    for (int m = 0; m < 8; ++m) {
      float am[4] = {0.f, 0.f, 0.f, 0.f};
#pragma unroll
      for (int n = 0; n < 4; ++n) {
        const int cu = ((wgn - 2) << 6) + n * 16 + r15;    // 0..127
        const float wsc = wgs[INTER + nt * 128 + cu];
#pragma unroll
        for (int r = 0; r < 4; ++r) {
          const int rowl = (wgm << 7) + m * 16 + rq + r;
          const int grow = mt * 256 + rowl;
          const float uv = (float)acc[m][n][r] * xs[grow] * wsc;
          const float g = gs[rowl * 128 + (cu ^ (((rowl >> 2) & 1) << 4))];
          const float a = g / (1.f + __expf(-g)) * uv;
          act[(size_t)grow * INTER + nt * 128 + cu] = f2bf(a);
          am[r] = fmaxf(am[r], __builtin_fabsf(a));
        }
      }
#pragma unroll
      for (int r = 0; r < 4; ++r) {
#pragma unroll
        for (int off = 1; off < 16; off <<= 1)
          am[r] = fmaxf(am[r], __shfl_xor(am[r], off, 64));
      }
      if (r15 == 0) {
#pragma unroll
        for (int r = 0; r < 4; ++r)
          atomicMax((int*)&mx[mt * 256 + (wgm << 7) + m * 16 + rq + r],
                    __float_as_int(am[r]));
      }
    }
  }
}

// ---------------------------------------------------------------------------
// quant: q2 = clip(rint(act * 127/mx)); writes int8 in tiled+swizzled layout.
// ---------------------------------------------------------------------------
__global__ __launch_bounds__(256) void quant_k(
    const unsigned short* __restrict__ act, const float* __restrict__ mx,
    uint8_t* __restrict__ q2t)
{
  const long u = (long)blockIdx.x * 256 + threadIdx.x;
  const long tile = u >> 10;
  const int within = (int)(u & 1023);
  const int row = within >> 3;
  const int swc = (within & 7) << 4;
  const int col = swc ^ ((row & 7) << 4);
  const long tR = tile / KT2;
  const long tK = tile - tR * KT2;
  const int grow = (int)tR * 128 + row;
  const int gcol = (int)tK * 128 + col;
  const unsigned short* ap = act + (size_t)grow * INTER + gcol;
  const float inv = 127.0f / fmaxf(mx[grow], 1e-30f);
  u16x8 a0 = *reinterpret_cast<const u16x8*>(ap);
  u16x8 a1 = *reinterpret_cast<const u16x8*>(ap + 8);
  i32x4 o;
#pragma unroll
  for (int q = 0; q < 4; ++q) {
    uint32_t d = 0;
#pragma unroll
    for (int b = 0; b < 4; ++b) {
      const int j = q * 4 + b;
      uint32_t aB = (j < 8) ? a0[j] : a1[j - 8];
      float af = __uint_as_float(aB << 16);
      float r = rintf(af * inv);
      r = fminf(fmaxf(r, -127.f), 127.f);
      d |= ((uint32_t)((int)r & 255)) << (8 * b);
    }
    o[q] = (int)d;
  }
  *reinterpret_cast<i32x4*>(q2t + tile * 16384 + (long)within * 16) = o;
}

// ---------------------------------------------------------------------------
// GEMM2: 128x256 tile, 8 waves (2Mx4N), same pipelined core. K = INTER.
// out[row][col] = acc * (mx[row]/127) * wds[col], f32.
// ---------------------------------------------------------------------------
__global__ __launch_bounds__(512, 2) void gemm2_k(
    const uint8_t* __restrict__ q2t, const uint8_t* __restrict__ wd8t,
    const float* __restrict__ mx, const float* __restrict__ wds,
    float* __restrict__ out)
{
  __shared__ uint8_t sm[98304];
  const int tid = threadIdx.x;
  const int lane = tid & 63, wid = tid >> 6;
  const int wgm = wid >> 2, wgn = wid & 3;
  const int mt = blockIdx.x, nt = blockIdx.y;
  const int r15 = lane & 15;
  const int sxo = (r15 & 7) << 4;
  const int khi = (lane >> 4) << 4;

  const uint8_t* pA  = q2t  + ((size_t)mt           * KT2) * 16384 + tid * 16;
  const uint8_t* pB0 = wd8t + ((size_t)(2 * nt)     * KT2) * 16384 + tid * 16;
  const uint8_t* pB1 = wd8t + ((size_t)(2 * nt + 1) * KT2) * 16384 + tid * 16;

  const int aoff = ((wgm << 6) + r15) << 7;            // (wgm*64+r15)*128
  const int boff = 16384 + (((wgn << 6) + r15) << 7);

  i32x4 acc[4][4] = {};

#define STAGE2(kt, buf) do {                                   \
    uint8_t* l = sm + (buf) * 49152;                           \
    const size_t S = (size_t)(kt) * 16384;                     \
    GLD16(pA  + S,        l + tid * 16);                       \
    GLD16(pA  + S + 8192, l + tid * 16 + 8192);                \
    GLD16(pB0 + S,        l + tid * 16 + 16384);               \
    GLD16(pB0 + S + 8192, l + tid * 16 + 24576);               \
    GLD16(pB1 + S,        l + tid * 16 + 32768);               \
    GLD16(pB1 + S + 8192, l + tid * 16 + 40960);               \
  } while (0)

  STAGE2(0, 0);
  __syncthreads();

  for (int kt = 0; kt < KT2; ++kt) {
    if (kt + 1 < KT2) STAGE2(kt + 1, (kt + 1) & 1);
    const uint8_t* bufc = sm + (kt & 1) * 49152;
#pragma unroll
    for (int kk = 0; kk < 2; ++kk) {
      const int cs = (khi + kk * 64) ^ sxo;
      i32x4 av[4], bv[4];
#pragma unroll
      for (int n = 0; n < 4; ++n)
        bv[n] = *reinterpret_cast<const i32x4*>(bufc + boff + n * 2048 + cs);
#pragma unroll
      for (int m = 0; m < 4; ++m)
        av[m] = *reinterpret_cast<const i32x4*>(bufc + aoff + m * 2048 + cs);
      __builtin_amdgcn_s_setprio(1);
#pragma unroll
      for (int m = 0; m < 4; ++m)
#pragma unroll
        for (int n = 0; n < 4; ++n)
          acc[m][n] = __builtin_amdgcn_mfma_i32_16x16x64_i8(
              av[m], bv[n], acc[m][n], 0, 0, 0);
      __builtin_amdgcn_s_setprio(0);
    }
    __syncthreads();
  }
#undef STAGE2

  const int rq = (lane >> 4) << 2;
#pragma unroll
  for (int m = 0; m < 4; ++m) {
#pragma unroll
    for (int r = 0; r < 4; ++r) {
      const int rowl = (wgm << 6) + m * 16 + rq + r;
      const int grow = mt * 128 + rowl;
      const float s2 = mx[grow] * (1.0f / 127.0f);
      float* op = out + (size_t)grow * HID + nt * 256 + (wgn << 6) + r15;
      const float* wp = wds + nt * 256 + (wgn << 6) + r15;
#pragma unroll
      for (int n = 0; n < 4; ++n)
        op[n * 16] = (float)acc[m][n][r] * s2 * wp[n * 16];
    }
  }
}

// ---------------------------------------------------------------------------
extern "C" void kernel_launch(void* const* d_in, const int* in_sizes, int n_in,
                              void* d_out, int out_size, void* d_ws, size_t ws_size,
                              hipStream_t stream)
{
  const int*   x_q = (const int*)d_in[0];
  const float* xs  = (const float*)d_in[1];
  const int*   wg  = (const int*)d_in[2];
  const float* wgs = (const float*)d_in[3];
  const int*   wd  = (const int*)d_in[4];
  const float* wds = (const float*)d_in[5];
  float* out = (float*)d_out;

  uint8_t* ws = (uint8_t*)d_ws;
  uint8_t* x8t  = ws;                                        //   8,388,608
  uint8_t* wg8t = x8t + 8388608;                             //  90,177,536
  uint8_t* wd8t = wg8t + 90177536;                           //  45,088,768
  unsigned short* act = (unsigned short*)(wd8t + 45088768);  //  45,088,768
  float* mx = (float*)((uint8_t*)act + 45088768);            //       8,192
  uint8_t* q2t = (uint8_t*)mx + 8192;                        //  22,544,384
  // total ~211.3 MB

  zero_mx<<<2, 1024, 0, stream>>>(mx);
  pack_tiled<<<2048, 256, 0, stream>>>(x_q, x8t, HID, KT1);
  pack_tiled<<<22016, 256, 0, stream>>>(wg, wg8t, HID, KT1);
  pack_tiled<<<11008, 256, 0, stream>>>(wd, wd8t, INTER, KT2);

  gemm1_k<<<dim3(8, 86), 512, 0, stream>>>(x8t, wg8t, xs, wgs, act, mx);
  quant_k<<<5504, 256, 0, stream>>>(act, mx, q2t);
  gemm2_k<<<dim3(16, 16), 512, 0, stream>>>(q2t, wd8t, mx, wds, out);
}